// Round 8
// baseline (180.485 us; speedup 1.0000x reference)
//
#include <hip/hip_runtime.h>

#define DIM 128
#define EPS 1e-5f

typedef short        bf16x8 __attribute__((ext_vector_type(8)));
typedef unsigned int u32x4  __attribute__((ext_vector_type(4)));
typedef float        f32x2  __attribute__((ext_vector_type(2)));
typedef float        f32x4  __attribute__((ext_vector_type(4)));

__device__ __forceinline__ unsigned short f2b(float f) {
    unsigned int u = __builtin_bit_cast(unsigned int, f);
    unsigned int r = (u + 0x7FFFu + ((u >> 16) & 1u)) >> 16;   // RNE
    return (unsigned short)r;
}

// ---------------------------------------------------------------------------
// K0a: segment boundaries. bounds[b] = first n with batch[n] >= b.
// ---------------------------------------------------------------------------
__global__ __launch_bounds__(256) void k_bounds(
    const int* __restrict__ batch, int* __restrict__ bounds, int n_nodes, int nb)
{
    const int idx = blockIdx.x * blockDim.x + threadIdx.x;
    if (idx > n_nodes) return;
    const int cur  = (idx < n_nodes) ? batch[idx] : nb;
    const int prev = (idx > 0) ? batch[idx - 1] : -1;
    for (int b = prev + 1; b <= cur; ++b) bounds[b] = idx;
}

// ---------------------------------------------------------------------------
// K0b: convert W1,W2 (f32, row-major [128][128]) to bf16 copies in ws.
// Wb[0..16383] = W1, Wb[16384..32767] = W2. 64 KB total -> L2-resident.
// ---------------------------------------------------------------------------
__global__ __launch_bounds__(256) void k_prep(
    const float* __restrict__ W1, const float* __restrict__ W2,
    unsigned short* __restrict__ Wb)
{
    const int i = blockIdx.x * blockDim.x + threadIdx.x;   // 0..32767
    if (i >= 32768) return;
    const float v = (i < 16384) ? W1[i] : W2[i - 16384];
    Wb[i] = f2b(v);
}

// ---------------------------------------------------------------------------
// K1: fully fused, ONE WAVE PER GRAPH, zero barriers.
//   pool (lane owns cols 2l,2l+1) -> per-wave MFMA MLP (x broadcast across
//   all 16 A-rows; weights bf16 from L2) -> re-walk segment (cache-warm) and
//   NT-store h_out. 8192 waves fill the machine; no inter-wave coupling.
// MFMA mapping notes: A and B frags share the element->k bijection
//   k = kt*32 + kgrp*8 + i, so the contraction is correct for any HW
//   k-permutation. C/D (m89-verified): col = lane&15, row = (lane>>4)*4+reg;
//   A-rows are identical (broadcast x) so every lane holds y[t*16+(lane&15)].
// ---------------------------------------------------------------------------
__global__ __launch_bounds__(256, 6) void k_fused(
    const float* __restrict__ h, const int* __restrict__ bounds,
    const float* __restrict__ vn, const unsigned short* __restrict__ Wb,
    const float* __restrict__ b1, const float* __restrict__ lng,
    const float* __restrict__ lnb, const float* __restrict__ b2v,
    float* __restrict__ vn_out, float* __restrict__ h_out)
{
    const int wid  = (blockIdx.x * blockDim.x + threadIdx.x) >> 6;  // graph
    const int lane = threadIdx.x & 63;
    const int s = bounds[wid], e = bounds[wid + 1];

    // ---- phase 1: pool. lane owns cols 2l, 2l+1; 8 rows in flight ----
    const f32x2 z2 = (f32x2){0.f, 0.f};
    f32x2 a0 = z2, a1 = z2, a2 = z2, a3 = z2, a4 = z2, a5 = z2, a6 = z2, a7 = z2;
    int n = s;
    for (; n + 8 <= e; n += 8) {
        const float* p = h + (size_t)n * DIM + lane * 2;
        a0 += *reinterpret_cast<const f32x2*>(p);
        a1 += *reinterpret_cast<const f32x2*>(p + DIM);
        a2 += *reinterpret_cast<const f32x2*>(p + 2 * DIM);
        a3 += *reinterpret_cast<const f32x2*>(p + 3 * DIM);
        a4 += *reinterpret_cast<const f32x2*>(p + 4 * DIM);
        a5 += *reinterpret_cast<const f32x2*>(p + 5 * DIM);
        a6 += *reinterpret_cast<const f32x2*>(p + 6 * DIM);
        a7 += *reinterpret_cast<const f32x2*>(p + 7 * DIM);
    }
    for (; n < e; ++n)
        a0 += *reinterpret_cast<const f32x2*>(h + (size_t)n * DIM + lane * 2);
    a0 += a1; a2 += a3; a4 += a5; a6 += a7; a0 += a2; a4 += a6; a0 += a4;

    const int cnt = e - s;
    const float inv = 1.0f / (float)(cnt > 1 ? cnt : 1);
    f32x2 vv = *reinterpret_cast<const f32x2*>(vn + (size_t)wid * DIM + lane * 2);
    // packed bf16 pair: x[2l] | x[2l+1]<<16
    const unsigned int x01 =
        (unsigned int)f2b(fmaf(a0[0], inv, vv[0])) |
        ((unsigned int)f2b(fmaf(a0[1], inv, vv[1])) << 16);

    // ---- phase 2: per-wave MLP ----
    const int row16 = lane & 15;
    const int kgrp  = lane >> 4;

    // A-frags: x broadcast to all 16 rows. element pair c2 of frag kt comes
    // from lane kt*16 + kgrp*4 + c2 (uniform across row16).
    bf16x8 af[4];
    #pragma unroll
    for (int kt = 0; kt < 4; ++kt) {
        const int sbase = kt * 16 + kgrp * 4;
        u32x4 w;
        w[0] = __shfl(x01, sbase + 0);
        w[1] = __shfl(x01, sbase + 1);
        w[2] = __shfl(x01, sbase + 2);
        w[3] = __shfl(x01, sbase + 3);
        af[kt] = __builtin_bit_cast(bf16x8, w);
    }

    f32x4 C[8];
    #pragma unroll
    for (int t = 0; t < 8; ++t) C[t] = (f32x4){0.f, 0.f, 0.f, 0.f};
    #pragma unroll
    for (int t = 0; t < 8; ++t) {
        const unsigned short* wr = Wb + (size_t)(t * 16 + row16) * DIM + kgrp * 8;
        #pragma unroll
        for (int kt = 0; kt < 4; ++kt) {
            bf16x8 bf = *reinterpret_cast<const bf16x8*>(wr + kt * 32);
            C[t] = __builtin_amdgcn_mfma_f32_16x16x32_bf16(af[kt], bf, C[t], 0, 0, 0);
        }
    }

    // per-lane feature params (feature f = t*16 + row16)
    float y[8];
    float gf[8], bf_[8], b2f8[8];
    #pragma unroll
    for (int t = 0; t < 8; ++t) {
        const int f = t * 16 + row16;
        y[t]    = C[t][0] + b1[f];
        gf[t]   = lng[f];
        bf_[t]  = lnb[f];
        b2f8[t] = b2v[f];
    }

    // LayerNorm over 128 features: per-lane partial over t, then 16-lane reduce
    float sm = 0.f, ss = 0.f;
    #pragma unroll
    for (int t = 0; t < 8; ++t) { sm += y[t]; ss += y[t] * y[t]; }
    #pragma unroll
    for (int m = 1; m <= 8; m <<= 1) {
        sm += __shfl_xor(sm, m);
        ss += __shfl_xor(ss, m);
    }
    const float mu  = sm * (1.0f / 128.0f);
    const float var = ss * (1.0f / 128.0f) - mu * mu;
    const float rs  = rsqrtf(var + EPS);

    // z (relu'd, bf16-paired across t: zp[kt] = z[2kt] | z[2kt+1]<<16)
    unsigned int zp[4];
    #pragma unroll
    for (int kt = 0; kt < 4; ++kt) {
        float zl = fmaxf((y[2 * kt]     - mu) * rs * gf[2 * kt]     + bf_[2 * kt],     0.f);
        float zh = fmaxf((y[2 * kt + 1] - mu) * rs * gf[2 * kt + 1] + bf_[2 * kt + 1], 0.f);
        zp[kt] = (unsigned int)f2b(zl) | ((unsigned int)f2b(zh) << 16);
    }

    // layer-2 A-frags: element i of frag kt is z[kt*32 + kgrp*8 + i].
    // f = kt*32+kgrp*8+i -> t = 2kt + (kgrp>>1), src lane = (kgrp&1)*8 + i.
    const unsigned int hsel = kgrp >> 1;          // which 16-bit half of zp
    const int sbase2 = (kgrp & 1) * 8;
    bf16x8 zf[4];
    #pragma unroll
    for (int kt = 0; kt < 4; ++kt) {
        u32x4 w;
        #pragma unroll
        for (int c2 = 0; c2 < 4; ++c2) {
            unsigned int q0 = __shfl(zp[kt], sbase2 + 2 * c2);
            unsigned int q1 = __shfl(zp[kt], sbase2 + 2 * c2 + 1);
            unsigned int e0 = hsel ? (q0 >> 16) : (q0 & 0xFFFFu);
            unsigned int e1 = hsel ? (q1 >> 16) : (q1 & 0xFFFFu);
            w[c2] = e0 | (e1 << 16);
        }
        zf[kt] = __builtin_bit_cast(bf16x8, w);
    }

    f32x4 C2[8];
    #pragma unroll
    for (int t = 0; t < 8; ++t) C2[t] = (f32x4){0.f, 0.f, 0.f, 0.f};
    #pragma unroll
    for (int t = 0; t < 8; ++t) {
        const unsigned short* wr =
            Wb + 16384 + (size_t)(t * 16 + row16) * DIM + kgrp * 8;
        #pragma unroll
        for (int kt = 0; kt < 4; ++kt) {
            bf16x8 bf = *reinterpret_cast<const bf16x8*>(wr + kt * 32);
            C2[t] = __builtin_amdgcn_mfma_f32_16x16x32_bf16(zf[kt], bf, C2[t], 0, 0, 0);
        }
    }

    // vn_out store (lanes 0-15 hold the unique copy; 16 lanes x 4B = 64B/t)
    if (lane < 16) {
        #pragma unroll
        for (int t = 0; t < 8; ++t)
            vn_out[(size_t)wid * DIM + t * 16 + row16] = C2[t][0] + b2f8[t];
    }

    // make stores visible, then cross-lane redistribute via L2 read-back
    asm volatile("s_waitcnt vmcnt(0)" ::: "memory");
    volatile const float* vo = vn_out + (size_t)wid * DIM + lane * 2;
    const float w0 = vo[0];
    const float w1 = vo[1];
    const f32x2 w = (f32x2){w0, w1};

    // ---- phase 3: h_out = h + o, segment rows are L2/L3-warm ----
    n = s;
    for (; n + 4 <= e; n += 4) {
        const float* p = h + (size_t)n * DIM + lane * 2;
        f32x2 r0 = *reinterpret_cast<const f32x2*>(p);
        f32x2 r1 = *reinterpret_cast<const f32x2*>(p + DIM);
        f32x2 r2 = *reinterpret_cast<const f32x2*>(p + 2 * DIM);
        f32x2 r3 = *reinterpret_cast<const f32x2*>(p + 3 * DIM);
        float* q = h_out + (size_t)n * DIM + lane * 2;
        __builtin_nontemporal_store(r0 + w, reinterpret_cast<f32x2*>(q));
        __builtin_nontemporal_store(r1 + w, reinterpret_cast<f32x2*>(q + DIM));
        __builtin_nontemporal_store(r2 + w, reinterpret_cast<f32x2*>(q + 2 * DIM));
        __builtin_nontemporal_store(r3 + w, reinterpret_cast<f32x2*>(q + 3 * DIM));
    }
    for (; n < e; ++n) {
        const float* p = h + (size_t)n * DIM + lane * 2;
        f32x2 r0 = *reinterpret_cast<const f32x2*>(p);
        float* q = h_out + (size_t)n * DIM + lane * 2;
        __builtin_nontemporal_store(r0 + w, reinterpret_cast<f32x2*>(q));
    }
}

// ---------------------------------------------------------------------------
extern "C" void kernel_launch(void* const* d_in, const int* in_sizes, int n_in,
                              void* d_out, int out_size, void* d_ws, size_t ws_size,
                              hipStream_t stream)
{
    const float* h    = (const float*)d_in[0];
    const int*   bat  = (const int*)d_in[1];
    const float* vn   = (const float*)d_in[2];
    const float* W1   = (const float*)d_in[3];
    const float* b1   = (const float*)d_in[4];
    const float* lng  = (const float*)d_in[5];
    const float* lnb  = (const float*)d_in[6];
    const float* W2   = (const float*)d_in[7];
    const float* b2v  = (const float*)d_in[8];

    const int n_nodes = in_sizes[0] / DIM;   // 500000
    const int nb      = in_sizes[2] / DIM;   // 8192

    float* out    = (float*)d_out;           // f32 output buffer
    float* h_out  = out;
    float* vn_out = out + (size_t)n_nodes * DIM;

    int* bounds = (int*)d_ws;                               // (nb+1) ints
    unsigned short* Wb = (unsigned short*)
        ((char*)d_ws + (((size_t)(nb + 1) * 4 + 255) & ~(size_t)255));  // 64 KB

    k_bounds<<<(n_nodes + 256) / 256, 256, 0, stream>>>(bat, bounds, n_nodes, nb);
    k_prep<<<128, 256, 0, stream>>>(W1, W2, Wb);
    k_fused<<<nb * 64 / 256, 256, 0, stream>>>(h, bounds, vn, Wb,
                                               b1, lng, lnb, b2v, vn_out, h_out);
}